// Round 4
// baseline (491.742 us; speedup 1.0000x reference)
//
#include <hip/hip_runtime.h>

// Problem constants
#define B_   64
#define N_   256
#define E_   1024
#define H_   16
#define D_   64
#define S_   257
#define M_   16448      // B_*S_
#define MP2  16640      // padded to 65*256
#define N3_  3072
#define K_   1024

typedef unsigned short u16;
typedef unsigned int   u32;
typedef __bf16 bf16x8 __attribute__((ext_vector_type(8)));
typedef float  f32x4  __attribute__((ext_vector_type(4)));

__device__ inline u16 f2bf(float f) {
  union { float f; u32 u; } a; a.f = f;
  return (u16)((a.u + 0x7FFFu + ((a.u >> 16) & 1u)) >> 16);
}
__device__ inline float bf2f(u16 h) {
  union { u32 u; float f; } a; a.u = ((u32)h) << 16; return a.f;
}
__device__ inline void gload_lds16(const void* g, void* l) {
  __builtin_amdgcn_global_load_lds((const __attribute__((address_space(1))) void*)g,
                                   (__attribute__((address_space(3))) void*)l, 16, 0, 0);
}

// ---------------- prep: convert in_proj_w (3E x E) f32 -> bf16 ----------------
__global__ __launch_bounds__(256) void prep_w(const float* __restrict__ w, u16* __restrict__ o) {
  size_t i = ((size_t)blockIdx.x * 256 + threadIdx.x) * 4;
  float4 f = *(const float4*)(w + i);
  ushort4 v;
  v.x = f2bf(f.x); v.y = f2bf(f.y); v.z = f2bf(f.z); v.w = f2bf(f.w);
  *(ushort4*)(o + i) = v;
}

// ---------------- build x = concat(cls, news) + pos_emb, bf16, padded rows zeroed ----------------
__global__ __launch_bounds__(256) void build_x(const float* __restrict__ news,
                                               const float* __restrict__ cls,
                                               const float* __restrict__ pos,
                                               u16* __restrict__ x) {
  const int row = blockIdx.x;          // 0..16639
  const int e = threadIdx.x * 4;
  float4 v = make_float4(0.f, 0.f, 0.f, 0.f);
  if (row < M_) {
    const int b = row / S_;
    const int s = row - b * S_;
    float4 pe = *(const float4*)(pos + (size_t)s * E_ + e);
    float4 xv = (s == 0) ? *(const float4*)(cls + e)
                         : *(const float4*)(news + ((size_t)b * N_ + (s - 1)) * E_ + e);
    v.x = xv.x + pe.x; v.y = xv.y + pe.y; v.z = xv.z + pe.z; v.w = xv.w + pe.w;
  }
  ushort4 o;
  o.x = f2bf(v.x); o.y = f2bf(v.y); o.z = f2bf(v.z); o.w = f2bf(v.w);
  *(ushort4*)(x + (size_t)row * E_ + e) = o;
}

// ---------------- mask: detect dtype (int32 / uint8 / float32) -> int32 ----------------
__global__ __launch_bounds__(256) void mask_prep(const void* __restrict__ src, int* __restrict__ dst) {
  const int t = threadIdx.x;
  const u32* wsrc = (const u32*)src;
  u32 flag = 0;
  for (int i = t; i < 4096; i += 256) {
    u32 v = wsrc[i];
    if (v == 0x3F800000u) flag |= 2u;
    else if (v > 1u) flag |= 1u;
  }
  __shared__ u32 fsh;
  if (t == 0) fsh = 0;
  __syncthreads();
  if (flag) atomicOr(&fsh, flag);
  __syncthreads();
  const u32 f = fsh;
  const int mode = (f & 2u) ? 2 : ((f & 1u) ? 1 : 0);
  for (int i = t; i < B_ * N_; i += 256) {
    int m;
    if (mode == 0)      m = (wsrc[i] != 0u);
    else if (mode == 2) m = (((const float*)src)[i] != 0.f);
    else                m = (((const unsigned char*)src)[i] != 0);
    dst[i] = m;
  }
}

// ---------------- QKV GEMM: 256x256x64 deep-pipelined, fragment-major LDS ----------------
// C[MP2 x N3_] = A[MP2 x K_] * Bw[N3_ x K_]^T + bias, bf16 out.
// 512 threads = 8 waves (wm = w>>2 in {0,1}, wn = w&3 in {0..3}); per-wave 128x64 output.
// LDS holds each K-tile in FRAGMENT-MAJOR order: 32 blocks of 1KB; block (g*2+ks)
// holds lanes' bf16x8 fragments for 16-row group g, k-slice ks. Staged via
// global_load_lds with per-lane source addressing -> linear LDS writes AND linear
// ds_read_b128 (zero bank conflicts). One barrier per K-tile; next tile's 8 loads
// issued before this tile's reads+MFMA (loads in flight across the whole tile).
__global__ __launch_bounds__(512, 2) void gemm_qkv(const u16* __restrict__ A,
                                                   const u16* __restrict__ Bw,
                                                   const float* __restrict__ bias,
                                                   u16* __restrict__ C) {
  __shared__ u16 ldsA[2][16384];   // 2 x 32 KB
  __shared__ u16 ldsB[2][16384];   // 2 x 32 KB  (total 128 KB)
  const int t = threadIdx.x;
  const int w = t >> 6, l = t & 63;
  const int wm = w >> 2, wn = w & 3;

  // bijective XCD swizzle (nwg=780: q=97,r=4), bn-fastest (each XCD owns an A row-band)
  const int orig = blockIdx.x;
  const int xcd = orig & 7, idx = orig >> 3;
  const int wgid = (xcd < 4 ? xcd * 98 : 392 + (xcd - 4) * 97) + idx;
  const int bm = wgid / 12, bn = wgid % 12;

  const u16* Abase = A + (size_t)bm * 256 * K_;
  const u16* Bbase = Bw + (size_t)bn * 256 * K_;

  // per-lane staging source offset: wave w, chunk c stages block c*8+w
  //   group g = (c*8+w)>>1 = c*4 + (w>>1), ks = w&1
  //   row = g*16 + (l&15), col = ks*32 + (l>>4)*8
  const size_t laneOff = (size_t)((w >> 1) * 16 + (l & 15)) * K_ + (w & 1) * 32 + (l >> 4) * 8;
  const int dstOff = w * 1024;     // byte offset of this wave's 1KB block within a chunk

  f32x4 acc[8][4] = {};

#define STAGE(buf, k0)                                                              \
  {                                                                                 \
    _Pragma("unroll")                                                               \
    for (int c = 0; c < 4; ++c) {                                                   \
      gload_lds16(Abase + laneOff + (size_t)c * (64 * K_) + (k0),                   \
                  (char*)ldsA + (buf) * 32768 + c * 8192 + dstOff);                 \
      gload_lds16(Bbase + laneOff + (size_t)c * (64 * K_) + (k0),                   \
                  (char*)ldsB + (buf) * 32768 + c * 8192 + dstOff);                 \
    }                                                                               \
  }

  STAGE(0, 0);
  __syncthreads();

  for (int kt = 0; kt < 16; ++kt) {
    const int buf = kt & 1;
    if (kt < 15) STAGE(buf ^ 1, (kt + 1) * 64);

    const u16* lA = ldsA[buf];
    const u16* lB = ldsB[buf];
    bf16x8 af[8][2], bfx[4][2];
#pragma unroll
    for (int a = 0; a < 8; ++a)
#pragma unroll
      for (int ks = 0; ks < 2; ++ks)
        af[a][ks] = *(const bf16x8*)&lA[(((wm * 8 + a) * 2 + ks) * 64 + l) * 8];
#pragma unroll
    for (int bq = 0; bq < 4; ++bq)
#pragma unroll
      for (int ks = 0; ks < 2; ++ks)
        bfx[bq][ks] = *(const bf16x8*)&lB[(((wn * 4 + bq) * 2 + ks) * 64 + l) * 8];

    __builtin_amdgcn_s_setprio(1);
#pragma unroll
    for (int a = 0; a < 8; ++a)
#pragma unroll
      for (int bq = 0; bq < 4; ++bq)
#pragma unroll
        for (int ks = 0; ks < 2; ++ks)
          acc[a][bq] = __builtin_amdgcn_mfma_f32_16x16x32_bf16(af[a][ks], bfx[bq][ks],
                                                               acc[a][bq], 0, 0, 0);
    __builtin_amdgcn_s_setprio(0);
    __syncthreads();
  }
#undef STAGE

  // epilogue: D layout col = l&15, row = (l>>4)*4 + j
  const int rg = l >> 4, cl = l & 15;
  const int row0 = bm * 256 + wm * 128 + rg * 4;
  const int col0 = bn * 256 + wn * 64 + cl;
#pragma unroll
  for (int bq = 0; bq < 4; ++bq) {
    const int col = col0 + bq * 16;
    const float bv = bias[col];
#pragma unroll
    for (int a = 0; a < 8; ++a) {
      const int row = row0 + a * 16;
#pragma unroll
      for (int j = 0; j < 4; ++j)
        C[(size_t)(row + j) * N3_ + col] = f2bf(acc[a][bq][j] + bv);
    }
  }
}

// ---------------- attention: register-resident scores, single staging barrier ----------------
__global__ __launch_bounds__(256) void attn_kernel(const u16* __restrict__ qkv,
                                                   const int* __restrict__ maskw,
                                                   float* __restrict__ attn,
                                                   float* __restrict__ ctx) {
  __shared__ u16 Ks[272 * 72];     // K rows, stride 72 (2-way bank alias only)
  __shared__ u16 Qs[64 * 72];
  __shared__ float msk[272];       // keep-multiplier: 1=keep, 0=drop
  __shared__ float p0[272];        // normalized CLS row (qt==0 only)
  __shared__ float red[4][64];
  const int qt = blockIdx.x, h = blockIdx.y, b = blockIdx.z;
  const int t = threadIdx.x;
  const int q0 = qt * 64;

  for (int c = t; c < 272 * 8; c += 256) {
    const int r = c >> 3, qq = c & 7;
    uint4 val = make_uint4(0, 0, 0, 0);
    if (r < S_)
      val = *(const uint4*)(qkv + (size_t)(b * S_ + r) * N3_ + E_ + h * 64 + qq * 8);
    *(uint4*)&Ks[r * 72 + qq * 8] = val;
  }
  for (int c = t; c < 64 * 8; c += 256) {
    const int r = c >> 3, qq = c & 7;
    const int gq = q0 + r;
    uint4 val = make_uint4(0, 0, 0, 0);
    if (gq < S_)
      val = *(const uint4*)(qkv + (size_t)(b * S_ + gq) * N3_ + h * 64 + qq * 8);
    *(uint4*)&Qs[r * 72 + qq * 8] = val;
  }
  for (int i = t; i < 272; i += 256) {
    float m = 0.f;
    if (i == 0) m = 1.f;
    else if (i < S_) m = maskw[b * N_ + i - 1] ? 0.f : 1.f;
    msk[i] = m;
  }
  __syncthreads();

  const int w = t >> 6, l = t & 63;
  const int cl = l & 15, rg = l >> 4;
  const int kc = rg * 8;

  const u16* qbase = &Qs[(w * 16 + cl) * 72 + kc];
  const bf16x8 qa0 = *(const bf16x8*)qbase;
  const bf16x8 qa1 = *(const bf16x8*)(qbase + 32);

  float ev[17][4];
  float sum[4] = {0.f, 0.f, 0.f, 0.f};
#pragma unroll
  for (int kt = 0; kt < 17; ++kt) {
    const u16* kbase = &Ks[(kt * 16 + cl) * 72 + kc];
    f32x4 a = {0.f, 0.f, 0.f, 0.f};
    a = __builtin_amdgcn_mfma_f32_16x16x32_bf16(qa0, *(const bf16x8*)kbase, a, 0, 0, 0);
    a = __builtin_amdgcn_mfma_f32_16x16x32_bf16(qa1, *(const bf16x8*)(kbase + 32), a, 0, 0, 0);
    const float m = msk[kt * 16 + cl];
#pragma unroll
    for (int j = 0; j < 4; ++j) {
      const float e = m * __expf(a[j] * 0.125f);
      ev[kt][j] = e;
      sum[j] += e;
    }
  }
  float inv[4];
#pragma unroll
  for (int j = 0; j < 4; ++j) {
#pragma unroll
    for (int o = 1; o < 16; o <<= 1) sum[j] += __shfl_xor(sum[j], o);
    inv[j] = 1.f / sum[j];
  }

  const int qrow0 = q0 + w * 16 + rg * 4;
  float* abase = attn + (size_t)(b * H_ + h) * S_ * S_;
#pragma unroll
  for (int j = 0; j < 4; ++j) {
    const int gq = qrow0 + j;
    if (gq < S_) {
      float* arow = abase + (size_t)gq * S_;
#pragma unroll
      for (int kt = 0; kt < 17; ++kt) {
        const int col = kt * 16 + cl;
        if (col < S_) arow[col] = ev[kt][j] * inv[j];
      }
    }
  }

  if (qt == 0) {
    if (w == 0 && rg == 0) {
      const float iv = inv[0];
#pragma unroll
      for (int kt = 0; kt < 17; ++kt) p0[kt * 16 + cl] = ev[kt][0] * iv;
    }
    __syncthreads();
    const int part = t >> 6, d = t & 63;
    float acc = 0.f;
    for (int k = part; k < S_; k += 4)
      acc = fmaf(p0[k], bf2f(qkv[(size_t)(b * S_ + k) * N3_ + 2 * E_ + h * 64 + d]), acc);
    red[part][d] = acc;
    __syncthreads();
    if (t < 64)
      ctx[(size_t)b * E_ + h * 64 + t] = red[0][t] + red[1][t] + red[2][t] + red[3][t];
  }
}

// ---------------- small GEMV for CLS rows ----------------
__global__ __launch_bounds__(256) void gemv_cls(const float* __restrict__ in,
                                                const float* __restrict__ W,
                                                const float* __restrict__ bias,
                                                float* __restrict__ out) {
  const int b = blockIdx.x, fc = blockIdx.y, t = threadIdx.x;
  __shared__ float xs[E_];
  for (int i = t; i < E_; i += 256) xs[i] = in[(size_t)b * E_ + i];
  __syncthreads();
  const int f = fc * 256 + t;
  const float4* wr = (const float4*)(W + (size_t)f * E_);
  float acc = 0.f;
#pragma unroll 4
  for (int e = 0; e < E_ / 4; ++e) {
    const float4 wv = wr[e];
    const float4 xv = *(const float4*)&xs[e * 4];
    acc = fmaf(wv.x, xv.x, acc);
    acc = fmaf(wv.y, xv.y, acc);
    acc = fmaf(wv.z, xv.z, acc);
    acc = fmaf(wv.w, xv.w, acc);
  }
  out[(size_t)b * E_ + f] = acc + bias[f];
}

// ---------------- LayerNorm + ReLU + L2-normalize for the 64 CLS rows ----------------
__global__ __launch_bounds__(256) void ln_relu_norm(const float* __restrict__ p,
                                                    const float* __restrict__ gamma,
                                                    const float* __restrict__ beta,
                                                    float* __restrict__ user) {
  const int b = blockIdx.x, t = threadIdx.x;
  const int w = t >> 6, l = t & 63;
  const float4 v = ((const float4*)(p + (size_t)b * E_))[t];
  float s = v.x + v.y + v.z + v.w;
  float s2 = v.x * v.x + v.y * v.y + v.z * v.z + v.w * v.w;
#pragma unroll
  for (int o = 1; o < 64; o <<= 1) { s += __shfl_xor(s, o); s2 += __shfl_xor(s2, o); }
  __shared__ float ss[4], ss2[4], qs[4];
  if (l == 0) { ss[w] = s; ss2[w] = s2; }
  __syncthreads();
  s = ss[0] + ss[1] + ss[2] + ss[3];
  s2 = ss2[0] + ss2[1] + ss2[2] + ss2[3];
  const float mu = s * (1.f / E_);
  const float var = s2 * (1.f / E_) - mu * mu;
  const float rstd = rsqrtf(var + 1e-5f);
  const float4 g = ((const float4*)gamma)[t];
  const float4 be = ((const float4*)beta)[t];
  float4 o;
  o.x = fmaxf((v.x - mu) * rstd * g.x + be.x, 0.f);
  o.y = fmaxf((v.y - mu) * rstd * g.y + be.y, 0.f);
  o.z = fmaxf((v.z - mu) * rstd * g.z + be.z, 0.f);
  o.w = fmaxf((v.w - mu) * rstd * g.w + be.w, 0.f);
  float q2 = o.x * o.x + o.y * o.y + o.z * o.z + o.w * o.w;
#pragma unroll
  for (int off = 1; off < 64; off <<= 1) q2 += __shfl_xor(q2, off);
  if (l == 0) qs[w] = q2;
  __syncthreads();
  q2 = qs[0] + qs[1] + qs[2] + qs[3];
  const float nrm = fmaxf(sqrtf(q2), 1e-12f);
  const float inv = 1.f / nrm;
  float4 u;
  u.x = o.x * inv; u.y = o.y * inv; u.z = o.z * inv; u.w = o.w * inv;
  ((float4*)(user + (size_t)b * E_))[t] = u;
}

extern "C" void kernel_launch(void* const* d_in, const int* in_sizes, int n_in,
                              void* d_out, int out_size, void* d_ws, size_t ws_size,
                              hipStream_t stream) {
  const float* news   = (const float*)d_in[0];
  const void*  maskp  = d_in[1];
  const float* cls    = (const float*)d_in[2];
  const float* pos    = (const float*)d_in[3];
  const float* w_in   = (const float*)d_in[4];
  const float* b_in   = (const float*)d_in[5];
  const float* w_out  = (const float*)d_in[6];
  const float* b_out  = (const float*)d_in[7];
  const float* w_proj = (const float*)d_in[8];
  const float* b_proj = (const float*)d_in[9];
  const float* gamma  = (const float*)d_in[10];
  const float* beta   = (const float*)d_in[11];

  char* ws = (char*)d_ws;
  // workspace layout (total ~143.5 MB)
  u16*  w_bf  = (u16*)(ws + 0);             //   6,291,456 B  (in_proj_w bf16)
  u16*  x_bf  = (u16*)(ws + 6291456);       //  34,078,720 B  (x bf16, MP2 x E_)
  u16*  qkv   = (u16*)(ws + 40370176);      // 102,236,160 B  (qkv bf16, MP2 x 3E)
  float* ctx  = (float*)(ws + 142606336);   //     262,144 B
  float* aoc  = (float*)(ws + 142868480);   //     262,144 B
  float* pcls = (float*)(ws + 143130624);   //     262,144 B
  int*  maskw = (int*)(ws + 143392768);     //      65,536 B

  float* user = (float*)d_out;
  float* attn = (float*)d_out + (size_t)B_ * E_;

  prep_w<<<3072, 256, 0, stream>>>(w_in, w_bf);
  build_x<<<MP2, 256, 0, stream>>>(news, cls, pos, x_bf);
  mask_prep<<<1, 256, 0, stream>>>(maskp, maskw);
  gemm_qkv<<<780, 512, 0, stream>>>(x_bf, w_bf, b_in, qkv);
  attn_kernel<<<dim3(5, H_, B_), 256, 0, stream>>>(qkv, maskw, attn, ctx);
  gemv_cls<<<dim3(B_, 4), 256, 0, stream>>>(ctx, w_out, b_out, aoc);
  gemv_cls<<<dim3(B_, 4), 256, 0, stream>>>(aoc, w_proj, b_proj, pcls);
  ln_relu_norm<<<B_, 256, 0, stream>>>(pcls, gamma, beta, user);
}

// Round 5
// 491.586 us; speedup vs baseline: 1.0003x; 1.0003x over previous
//
#include <hip/hip_runtime.h>

// Problem constants
#define B_   64
#define N_   256
#define E_   1024
#define H_   16
#define D_   64
#define S_   257
#define M_   16448      // B_*S_
#define MP2  16640      // padded to 65*256
#define N3_  3072
#define K_   1024

typedef unsigned short u16;
typedef unsigned int   u32;
typedef __bf16 bf16x8 __attribute__((ext_vector_type(8)));
typedef float  f32x4  __attribute__((ext_vector_type(4)));

__device__ inline u16 f2bf(float f) {
  union { float f; u32 u; } a; a.f = f;
  return (u16)((a.u + 0x7FFFu + ((a.u >> 16) & 1u)) >> 16);
}
__device__ inline float bf2f(u16 h) {
  union { u32 u; float f; } a; a.u = ((u32)h) << 16; return a.f;
}
__device__ inline void gload_lds16(const void* g, void* l) {
  __builtin_amdgcn_global_load_lds((const __attribute__((address_space(1))) void*)g,
                                   (__attribute__((address_space(3))) void*)l, 16, 0, 0);
}

// ---------------- prep: convert in_proj_w (3E x E) f32 -> bf16 ----------------
__global__ __launch_bounds__(256) void prep_w(const float* __restrict__ w, u16* __restrict__ o) {
  size_t i = ((size_t)blockIdx.x * 256 + threadIdx.x) * 4;
  float4 f = *(const float4*)(w + i);
  ushort4 v;
  v.x = f2bf(f.x); v.y = f2bf(f.y); v.z = f2bf(f.z); v.w = f2bf(f.w);
  *(ushort4*)(o + i) = v;
}

// ---------------- build x = concat(cls, news) + pos_emb, bf16, padded rows zeroed ----------------
__global__ __launch_bounds__(256) void build_x(const float* __restrict__ news,
                                               const float* __restrict__ cls,
                                               const float* __restrict__ pos,
                                               u16* __restrict__ x) {
  const int row = blockIdx.x;          // 0..16639
  const int e = threadIdx.x * 4;
  float4 v = make_float4(0.f, 0.f, 0.f, 0.f);
  if (row < M_) {
    const int b = row / S_;
    const int s = row - b * S_;
    float4 pe = *(const float4*)(pos + (size_t)s * E_ + e);
    float4 xv = (s == 0) ? *(const float4*)(cls + e)
                         : *(const float4*)(news + ((size_t)b * N_ + (s - 1)) * E_ + e);
    v.x = xv.x + pe.x; v.y = xv.y + pe.y; v.z = xv.z + pe.z; v.w = xv.w + pe.w;
  }
  ushort4 o;
  o.x = f2bf(v.x); o.y = f2bf(v.y); o.z = f2bf(v.z); o.w = f2bf(v.w);
  *(ushort4*)(x + (size_t)row * E_ + e) = o;
}

// ---------------- mask: detect dtype (int32 / uint8 / float32) -> int32 ----------------
__global__ __launch_bounds__(256) void mask_prep(const void* __restrict__ src, int* __restrict__ dst) {
  const int t = threadIdx.x;
  const u32* wsrc = (const u32*)src;
  u32 flag = 0;
  for (int i = t; i < 4096; i += 256) {
    u32 v = wsrc[i];
    if (v == 0x3F800000u) flag |= 2u;
    else if (v > 1u) flag |= 1u;
  }
  __shared__ u32 fsh;
  if (t == 0) fsh = 0;
  __syncthreads();
  if (flag) atomicOr(&fsh, flag);
  __syncthreads();
  const u32 f = fsh;
  const int mode = (f & 2u) ? 2 : ((f & 1u) ? 1 : 0);
  for (int i = t; i < B_ * N_; i += 256) {
    int m;
    if (mode == 0)      m = (wsrc[i] != 0u);
    else if (mode == 2) m = (((const float*)src)[i] != 0.f);
    else                m = (((const unsigned char*)src)[i] != 0);
    dst[i] = m;
  }
}

// ---------------- QKV GEMM: 256x256x64, fragment-major LDS, counted-vmcnt pipeline ----------------
// C[MP2 x N3_] = A[MP2 x K_] * Bw[N3_ x K_]^T + bias, bf16 out.
// 512 threads = 8 waves; per-wave 128x64 output. Fragment-major LDS: zero bank
// conflicts on both staging (linear global_load_lds dst) and ds_read_b128.
// Sync structure (T4): per K-tile
//   STAGE(next buf)                      // 8 global_load_lds, stay in flight
//   s_waitcnt vmcnt(8)                   // only waits for PREVIOUS tile's loads
//   s_barrier                            // buf ready on all waves
//   24x ds_read_b128 -> regs             // compiler inserts lgkmcnt before MFMA
//   setprio(1); 64x MFMA; setprio(0)
//   s_barrier                            // reads consumed -> safe to overwrite
// Never drains vmcnt to 0 in the main loop (m218: counted-vs-drain0 = +38..73%).
__global__ __launch_bounds__(512, 2) void gemm_qkv(const u16* __restrict__ A,
                                                   const u16* __restrict__ Bw,
                                                   const float* __restrict__ bias,
                                                   u16* __restrict__ C) {
  __shared__ u16 ldsA[2][16384];   // 2 x 32 KB
  __shared__ u16 ldsB[2][16384];   // 2 x 32 KB  (total 128 KB)
  const int t = threadIdx.x;
  const int w = t >> 6, l = t & 63;
  const int wm = w >> 2, wn = w & 3;

  // bijective XCD swizzle (nwg=780: q=97,r=4), bn-fastest (each XCD owns an A row-band)
  const int orig = blockIdx.x;
  const int xcd = orig & 7, idx = orig >> 3;
  const int wgid = (xcd < 4 ? xcd * 98 : 392 + (xcd - 4) * 97) + idx;
  const int bm = wgid / 12, bn = wgid % 12;

  const u16* Abase = A + (size_t)bm * 256 * K_;
  const u16* Bbase = Bw + (size_t)bn * 256 * K_;

  // per-lane staging source offset: wave w, chunk c stages block c*8+w
  //   group g = c*4 + (w>>1), ks = w&1 ; row = g*16 + (l&15), col = ks*32 + (l>>4)*8
  const size_t laneOff = (size_t)((w >> 1) * 16 + (l & 15)) * K_ + (w & 1) * 32 + (l >> 4) * 8;
  const int dstOff = w * 1024;     // byte offset of this wave's 1KB block within a chunk

  f32x4 acc[8][4] = {};

#define STAGE(buf, k0)                                                              \
  {                                                                                 \
    _Pragma("unroll")                                                               \
    for (int c = 0; c < 4; ++c) {                                                   \
      gload_lds16(Abase + laneOff + (size_t)c * (64 * K_) + (k0),                   \
                  (char*)ldsA + (buf) * 32768 + c * 8192 + dstOff);                 \
      gload_lds16(Bbase + laneOff + (size_t)c * (64 * K_) + (k0),                   \
                  (char*)ldsB + (buf) * 32768 + c * 8192 + dstOff);                 \
    }                                                                               \
  }

  STAGE(0, 0);

  for (int kt = 0; kt < 16; ++kt) {
    const int buf = kt & 1;
    if (kt < 15) {
      STAGE(buf ^ 1, (kt + 1) * 64);
      asm volatile("s_waitcnt vmcnt(8)" ::: "memory");   // previous tile's 8 loads done
    } else {
      asm volatile("s_waitcnt vmcnt(0)" ::: "memory");
    }
    __builtin_amdgcn_s_barrier();                         // buf ready (all waves)

    const u16* lA = ldsA[buf];
    const u16* lB = ldsB[buf];
    bf16x8 af[8][2], bfx[4][2];
#pragma unroll
    for (int a = 0; a < 8; ++a)
#pragma unroll
      for (int ks = 0; ks < 2; ++ks)
        af[a][ks] = *(const bf16x8*)&lA[(((wm * 8 + a) * 2 + ks) * 64 + l) * 8];
#pragma unroll
    for (int bq = 0; bq < 4; ++bq)
#pragma unroll
      for (int ks = 0; ks < 2; ++ks)
        bfx[bq][ks] = *(const bf16x8*)&lB[(((wn * 4 + bq) * 2 + ks) * 64 + l) * 8];

    __builtin_amdgcn_s_setprio(1);
#pragma unroll
    for (int a = 0; a < 8; ++a)
#pragma unroll
      for (int bq = 0; bq < 4; ++bq)
#pragma unroll
        for (int ks = 0; ks < 2; ++ks)
          acc[a][bq] = __builtin_amdgcn_mfma_f32_16x16x32_bf16(af[a][ks], bfx[bq][ks],
                                                               acc[a][bq], 0, 0, 0);
    __builtin_amdgcn_s_setprio(0);
    __builtin_amdgcn_s_barrier();                         // reads consumed everywhere
  }
#undef STAGE

  // epilogue: D layout col = l&15, row = (l>>4)*4 + j
  const int rg = l >> 4, cl = l & 15;
  const int row0 = bm * 256 + wm * 128 + rg * 4;
  const int col0 = bn * 256 + wn * 64 + cl;
#pragma unroll
  for (int bq = 0; bq < 4; ++bq) {
    const int col = col0 + bq * 16;
    const float bv = bias[col];
#pragma unroll
    for (int a = 0; a < 8; ++a) {
      const int row = row0 + a * 16;
#pragma unroll
      for (int j = 0; j < 4; ++j)
        C[(size_t)(row + j) * N3_ + col] = f2bf(acc[a][bq][j] + bv);
    }
  }
}

// ---------------- attention: register-resident scores, single staging barrier ----------------
__global__ __launch_bounds__(256) void attn_kernel(const u16* __restrict__ qkv,
                                                   const int* __restrict__ maskw,
                                                   float* __restrict__ attn,
                                                   float* __restrict__ ctx) {
  __shared__ u16 Ks[272 * 72];     // K rows, stride 72 (2-way bank alias only)
  __shared__ u16 Qs[64 * 72];
  __shared__ float msk[272];       // keep-multiplier: 1=keep, 0=drop
  __shared__ float p0[272];        // normalized CLS row (qt==0 only)
  __shared__ float red[4][64];
  const int qt = blockIdx.x, h = blockIdx.y, b = blockIdx.z;
  const int t = threadIdx.x;
  const int q0 = qt * 64;

  for (int c = t; c < 272 * 8; c += 256) {
    const int r = c >> 3, qq = c & 7;
    uint4 val = make_uint4(0, 0, 0, 0);
    if (r < S_)
      val = *(const uint4*)(qkv + (size_t)(b * S_ + r) * N3_ + E_ + h * 64 + qq * 8);
    *(uint4*)&Ks[r * 72 + qq * 8] = val;
  }
  for (int c = t; c < 64 * 8; c += 256) {
    const int r = c >> 3, qq = c & 7;
    const int gq = q0 + r;
    uint4 val = make_uint4(0, 0, 0, 0);
    if (gq < S_)
      val = *(const uint4*)(qkv + (size_t)(b * S_ + gq) * N3_ + h * 64 + qq * 8);
    *(uint4*)&Qs[r * 72 + qq * 8] = val;
  }
  for (int i = t; i < 272; i += 256) {
    float m = 0.f;
    if (i == 0) m = 1.f;
    else if (i < S_) m = maskw[b * N_ + i - 1] ? 0.f : 1.f;
    msk[i] = m;
  }
  __syncthreads();

  const int w = t >> 6, l = t & 63;
  const int cl = l & 15, rg = l >> 4;
  const int kc = rg * 8;

  const u16* qbase = &Qs[(w * 16 + cl) * 72 + kc];
  const bf16x8 qa0 = *(const bf16x8*)qbase;
  const bf16x8 qa1 = *(const bf16x8*)(qbase + 32);

  float ev[17][4];
  float sum[4] = {0.f, 0.f, 0.f, 0.f};
#pragma unroll
  for (int kt = 0; kt < 17; ++kt) {
    const u16* kbase = &Ks[(kt * 16 + cl) * 72 + kc];
    f32x4 a = {0.f, 0.f, 0.f, 0.f};
    a = __builtin_amdgcn_mfma_f32_16x16x32_bf16(qa0, *(const bf16x8*)kbase, a, 0, 0, 0);
    a = __builtin_amdgcn_mfma_f32_16x16x32_bf16(qa1, *(const bf16x8*)(kbase + 32), a, 0, 0, 0);
    const float m = msk[kt * 16 + cl];
#pragma unroll
    for (int j = 0; j < 4; ++j) {
      const float e = m * __expf(a[j] * 0.125f);
      ev[kt][j] = e;
      sum[j] += e;
    }
  }
  float inv[4];
#pragma unroll
  for (int j = 0; j < 4; ++j) {
#pragma unroll
    for (int o = 1; o < 16; o <<= 1) sum[j] += __shfl_xor(sum[j], o);
    inv[j] = 1.f / sum[j];
  }

  const int qrow0 = q0 + w * 16 + rg * 4;
  float* abase = attn + (size_t)(b * H_ + h) * S_ * S_;
#pragma unroll
  for (int j = 0; j < 4; ++j) {
    const int gq = qrow0 + j;
    if (gq < S_) {
      float* arow = abase + (size_t)gq * S_;
#pragma unroll
      for (int kt = 0; kt < 17; ++kt) {
        const int col = kt * 16 + cl;
        if (col < S_) arow[col] = ev[kt][j] * inv[j];
      }
    }
  }

  if (qt == 0) {
    if (w == 0 && rg == 0) {
      const float iv = inv[0];
#pragma unroll
      for (int kt = 0; kt < 17; ++kt) p0[kt * 16 + cl] = ev[kt][0] * iv;
    }
    __syncthreads();
    const int part = t >> 6, d = t & 63;
    float acc = 0.f;
    for (int k = part; k < S_; k += 4)
      acc = fmaf(p0[k], bf2f(qkv[(size_t)(b * S_ + k) * N3_ + 2 * E_ + h * 64 + d]), acc);
    red[part][d] = acc;
    __syncthreads();
    if (t < 64)
      ctx[(size_t)b * E_ + h * 64 + t] = red[0][t] + red[1][t] + red[2][t] + red[3][t];
  }
}

// ---------------- small GEMV for CLS rows ----------------
__global__ __launch_bounds__(256) void gemv_cls(const float* __restrict__ in,
                                                const float* __restrict__ W,
                                                const float* __restrict__ bias,
                                                float* __restrict__ out) {
  const int b = blockIdx.x, fc = blockIdx.y, t = threadIdx.x;
  __shared__ float xs[E_];
  for (int i = t; i < E_; i += 256) xs[i] = in[(size_t)b * E_ + i];
  __syncthreads();
  const int f = fc * 256 + t;
  const float4* wr = (const float4*)(W + (size_t)f * E_);
  float acc = 0.f;
#pragma unroll 4
  for (int e = 0; e < E_ / 4; ++e) {
    const float4 wv = wr[e];
    const float4 xv = *(const float4*)&xs[e * 4];
    acc = fmaf(wv.x, xv.x, acc);
    acc = fmaf(wv.y, xv.y, acc);
    acc = fmaf(wv.z, xv.z, acc);
    acc = fmaf(wv.w, xv.w, acc);
  }
  out[(size_t)b * E_ + f] = acc + bias[f];
}

// ---------------- LayerNorm + ReLU + L2-normalize for the 64 CLS rows ----------------
__global__ __launch_bounds__(256) void ln_relu_norm(const float* __restrict__ p,
                                                    const float* __restrict__ gamma,
                                                    const float* __restrict__ beta,
                                                    float* __restrict__ user) {
  const int b = blockIdx.x, t = threadIdx.x;
  const int w = t >> 6, l = t & 63;
  const float4 v = ((const float4*)(p + (size_t)b * E_))[t];
  float s = v.x + v.y + v.z + v.w;
  float s2 = v.x * v.x + v.y * v.y + v.z * v.z + v.w * v.w;
#pragma unroll
  for (int o = 1; o < 64; o <<= 1) { s += __shfl_xor(s, o); s2 += __shfl_xor(s2, o); }
  __shared__ float ss[4], ss2[4], qs[4];
  if (l == 0) { ss[w] = s; ss2[w] = s2; }
  __syncthreads();
  s = ss[0] + ss[1] + ss[2] + ss[3];
  s2 = ss2[0] + ss2[1] + ss2[2] + ss2[3];
  const float mu = s * (1.f / E_);
  const float var = s2 * (1.f / E_) - mu * mu;
  const float rstd = rsqrtf(var + 1e-5f);
  const float4 g = ((const float4*)gamma)[t];
  const float4 be = ((const float4*)beta)[t];
  float4 o;
  o.x = fmaxf((v.x - mu) * rstd * g.x + be.x, 0.f);
  o.y = fmaxf((v.y - mu) * rstd * g.y + be.y, 0.f);
  o.z = fmaxf((v.z - mu) * rstd * g.z + be.z, 0.f);
  o.w = fmaxf((v.w - mu) * rstd * g.w + be.w, 0.f);
  float q2 = o.x * o.x + o.y * o.y + o.z * o.z + o.w * o.w;
#pragma unroll
  for (int off = 1; off < 64; off <<= 1) q2 += __shfl_xor(q2, off);
  if (l == 0) qs[w] = q2;
  __syncthreads();
  q2 = qs[0] + qs[1] + qs[2] + qs[3];
  const float nrm = fmaxf(sqrtf(q2), 1e-12f);
  const float inv = 1.f / nrm;
  float4 u;
  u.x = o.x * inv; u.y = o.y * inv; u.z = o.z * inv; u.w = o.w * inv;
  ((float4*)(user + (size_t)b * E_))[t] = u;
}

extern "C" void kernel_launch(void* const* d_in, const int* in_sizes, int n_in,
                              void* d_out, int out_size, void* d_ws, size_t ws_size,
                              hipStream_t stream) {
  const float* news   = (const float*)d_in[0];
  const void*  maskp  = d_in[1];
  const float* cls    = (const float*)d_in[2];
  const float* pos    = (const float*)d_in[3];
  const float* w_in   = (const float*)d_in[4];
  const float* b_in   = (const float*)d_in[5];
  const float* w_out  = (const float*)d_in[6];
  const float* b_out  = (const float*)d_in[7];
  const float* w_proj = (const float*)d_in[8];
  const float* b_proj = (const float*)d_in[9];
  const float* gamma  = (const float*)d_in[10];
  const float* beta   = (const float*)d_in[11];

  char* ws = (char*)d_ws;
  // workspace layout (total ~143.5 MB)
  u16*  w_bf  = (u16*)(ws + 0);             //   6,291,456 B  (in_proj_w bf16)
  u16*  x_bf  = (u16*)(ws + 6291456);       //  34,078,720 B  (x bf16, MP2 x E_)
  u16*  qkv   = (u16*)(ws + 40370176);      // 102,236,160 B  (qkv bf16, MP2 x 3E)
  float* ctx  = (float*)(ws + 142606336);   //     262,144 B
  float* aoc  = (float*)(ws + 142868480);   //     262,144 B
  float* pcls = (float*)(ws + 143130624);   //     262,144 B
  int*  maskw = (int*)(ws + 143392768);     //      65,536 B

  float* user = (float*)d_out;
  float* attn = (float*)d_out + (size_t)B_ * E_;

  prep_w<<<3072, 256, 0, stream>>>(w_in, w_bf);
  build_x<<<MP2, 256, 0, stream>>>(news, cls, pos, x_bf);
  mask_prep<<<1, 256, 0, stream>>>(maskp, maskw);
  gemm_qkv<<<780, 512, 0, stream>>>(x_bf, w_bf, b_in, qkv);
  attn_kernel<<<dim3(5, H_, B_), 256, 0, stream>>>(qkv, maskw, attn, ctx);
  gemv_cls<<<dim3(B_, 4), 256, 0, stream>>>(ctx, w_out, b_out, aoc);
  gemv_cls<<<dim3(B_, 4), 256, 0, stream>>>(aoc, w_proj, b_proj, pcls);
  ln_relu_norm<<<B_, 256, 0, stream>>>(pcls, gamma, beta, user);
}